// Round 4
// baseline (3030.144 us; speedup 1.0000x reference)
//
#include <hip/hip_runtime.h>
#include <math.h>

// Problem constants
#define B_   256
#define T_   100
#define IN_  132
#define OUT_ 132
#define H_   1024
#define BH   ((size_t)B_ * H_)

typedef _Float16 f16;
typedef _Float16 f16x8 __attribute__((ext_vector_type(8)));
typedef float    f32x4 __attribute__((ext_vector_type(4)));

#define MFMA16(a, b, c) __builtin_amdgcn_mfma_f32_16x16x32_f16((a), (b), (c), 0, 0, 0)

#define AS1 __attribute__((address_space(1)))
#define AS3 __attribute__((address_space(3)))

__device__ __forceinline__ void gl_lds16(const void* g, void* l) {
    __builtin_amdgcn_global_load_lds((AS1 void*)g, (AS3 void*)l, 16, 0, 0);
}

__device__ __forceinline__ float sigmoidf_(float x) {
    return 1.0f / (1.0f + __expf(-x));
}
__device__ __forceinline__ float tanhf_(float x) {
    float e = __expf(2.0f * x);
    return 1.0f - 2.0f / (e + 1.0f);
}

// ---------------- prep kernels ----------------

__global__ void conv_pad(const float* __restrict__ src, f16* __restrict__ dst,
                         int src_rows, int src_k, int dst_k) {
    int k = blockIdx.x * 256 + threadIdx.x;
    int r = blockIdx.y;
    if (k >= dst_k) return;
    float v = (r < src_rows && k < src_k) ? src[(size_t)r * src_k + k] : 0.0f;
    dst[(size_t)r * dst_k + k] = (f16)v;
}

// WdT[m][k] = Wd[k][m], padded to k<160. grid (1, 1024), block 256
__global__ void convT_kernel(const float* __restrict__ Wd, f16* __restrict__ WdT) {
    int k = blockIdx.x * 256 + threadIdx.x;
    int m = blockIdx.y;
    if (k >= 160) return;
    float v = (k < IN_) ? Wd[(size_t)k * H_ + m] : 0.0f;
    WdT[(size_t)m * 160 + k] = (f16)v;
}

__global__ void bias_add_kernel(const float* __restrict__ a, const float* __restrict__ b,
                                float* __restrict__ dst, int n) {
    int i = blockIdx.x * 256 + threadIdx.x;
    if (i < n) dst[i] = a[i] + b[i];
}

// bfb[j] = sum_k Wih1[j][k] * bd[k]
__global__ void bfb_kernel(const float* __restrict__ Wih1, const float* __restrict__ bd,
                           float* __restrict__ bfb) {
    int j = blockIdx.x * 256 + threadIdx.x;
    if (j >= 4096) return;
    float s = 0.0f;
    for (int k = 0; k < IN_; ++k) s += Wih1[(size_t)j * IN_ + k] * bd[k];
    bfb[j] = s;
}

__global__ void zero_kernel(float* __restrict__ p, int n) {
    int i = blockIdx.x * blockDim.x + threadIdx.x;
    int st = gridDim.x * blockDim.x;
    for (; i < n; i += st) p[i] = 0.0f;
}

// Pack fp32 [4096][1024] weight into direct-fragment layout:
// Wpk[wsel][jt(64)][kk(32)][c(64)][64B], col c: gate=(c>>4)&3, jj=c&15,
// src row = gate*1024 + jt*16 + jj, k = kk*32 + ch*8 + e (plain order, no swizzle).
// grid (64 jt, 32 kk), block 256 (one thread = one 16B sub-chunk).
__global__ __launch_bounds__(256) void pack_w(const float* __restrict__ W,
                                              f16* __restrict__ Wpk, int wsel) {
    int jt = blockIdx.x, kk = blockIdx.y;
    f16* dst = Wpk + (((size_t)wsel * 64 + jt) * 32 + kk) * 2048;
    int u = threadIdx.x;
    int c = u >> 2, ch = u & 3;
    int row = ((c >> 4) & 3) * 1024 + jt * 16 + (c & 15);
    const float* s = W + (size_t)row * 1024 + kk * 32 + ch * 8;
    f16x8 v;
#pragma unroll
    for (int e = 0; e < 8; ++e) v[e] = (f16)s[e];
    *(f16x8*)(dst + (size_t)c * 32 + ch * 8) = v;
}

// Same but f16 source (for Wfb [4096][1024]).
__global__ __launch_bounds__(256) void pack_wf16(const f16* __restrict__ W,
                                                 f16* __restrict__ Wpk, int wsel) {
    int jt = blockIdx.x, kk = blockIdx.y;
    f16* dst = Wpk + (((size_t)wsel * 64 + jt) * 32 + kk) * 2048;
    int u = threadIdx.x;
    int c = u >> 2, ch = u & 3;
    int row = ((c >> 4) & 3) * 1024 + jt * 16 + (c & 15);
    f16x8 v = *(const f16x8*)(W + (size_t)row * 1024 + kk * 32 + ch * 8);
    *(f16x8*)(dst + (size_t)c * 32 + ch * 8) = v;
}

// Pack Wih1 fp32 [4096][132] -> W0pk[jt(64)][kk(5)][2048], k padded to 160.
// grid (64 jt, 5 kk), block 256.
__global__ __launch_bounds__(256) void pack_w0(const float* __restrict__ W,
                                               f16* __restrict__ W0pk) {
    int jt = blockIdx.x, kk = blockIdx.y;
    f16* dst = W0pk + ((size_t)jt * 5 + kk) * 2048;
    int u = threadIdx.x;
    int c = u >> 2, ch = u & 3;
    int row = ((c >> 4) & 3) * 1024 + jt * 16 + (c & 15);
    f16x8 v;
#pragma unroll
    for (int e = 0; e < 8; ++e) {
        int k = kk * 32 + ch * 8 + e;
        v[e] = (f16)((k < IN_) ? W[(size_t)row * IN_ + k] : 0.0f);
    }
    *(f16x8*)(dst + (size_t)c * 32 + ch * 8) = v;
}

// Pack seq fp32 [B][T][IN] -> seqpk[t][kk(5)][256 b][32] f16. grid (5, 100), block 256.
__global__ __launch_bounds__(256) void pack_seq(const float* __restrict__ seq,
                                                f16* __restrict__ seqpk) {
    int kt = blockIdx.x, t = blockIdx.y;
    int b = threadIdx.x;
    f16* d = seqpk + (((size_t)t * 5 + kt) * 256 + b) * 32;
#pragma unroll
    for (int ch = 0; ch < 4; ++ch) {
        f16x8 v;
#pragma unroll
        for (int e = 0; e < 8; ++e) {
            int k = kt * 32 + ch * 8 + e;
            v[e] = (f16)((k < IN_) ? seq[((size_t)b * T_ + t) * IN_ + k] : 0.0f);
        }
        *(f16x8*)(d + ch * 8) = v;
    }
}

// Wfb = W0(fp16,[4096][160]) @ WdT(fp16,[1024][160])^T -> [4096][1024] fp16
// grid (32 m-tiles, 8 n-tiles), block 256 (4 waves 2x2 of 64x64). One-time prep.
__global__ __launch_bounds__(256) void wfb_mfma(
    const f16* __restrict__ W0, const f16* __restrict__ WdT, f16* __restrict__ Wfb)
{
    const int m0 = blockIdx.x * 128;
    const int n0 = blockIdx.y * 128;
    const int tid  = threadIdx.x;
    const int lane = tid & 63;
    const int w    = tid >> 6;
    const int lx   = lane & 15;
    const int quad = lane >> 4;
    const int wrow = w >> 1, wcol = w & 1;

    __shared__ __align__(16) char lds[32768];   // 2 x (A 8KB + B 8KB)

    auto stA = [&](int kt, int buf) {
        char* base = lds + buf * 16384;
#pragma unroll
        for (int i = 0; i < 2; ++i) {
            int r  = w * 32 + i * 16 + (lane >> 2);
            int sg = (lane & 3) ^ (r & 3);
            const f16* g = W0 + (size_t)(m0 + r) * 160 + kt * 32 + sg * 8;
            gl_lds16(g, base + (size_t)(w * 32 + i * 16) * 64);
        }
    };
    auto stB = [&](int kt, int buf) {
        char* base = lds + 8192 + buf * 16384;
#pragma unroll
        for (int i = 0; i < 2; ++i) {
            int r  = w * 32 + i * 16 + (lane >> 2);
            int sg = (lane & 3) ^ (r & 3);
            const f16* g = WdT + (size_t)(n0 + r) * 160 + kt * 32 + sg * 8;
            gl_lds16(g, base + (size_t)(w * 32 + i * 16) * 64);
        }
    };

    f32x4 acc[4][4];
#pragma unroll
    for (int m = 0; m < 4; ++m)
#pragma unroll
        for (int n = 0; n < 4; ++n) acc[m][n] = (f32x4){0.f, 0.f, 0.f, 0.f};

    stA(0, 0); stB(0, 0);
    for (int kt = 0; kt < 5; ++kt) {
        __syncthreads();
        if (kt + 1 < 5) { stA(kt + 1, (kt + 1) & 1); stB(kt + 1, (kt + 1) & 1); }
        const char* bA = lds + (kt & 1) * 16384;
        const char* bB = lds + 8192 + (kt & 1) * 16384;
        f16x8 af[4], bf[4];
#pragma unroll
        for (int m = 0; m < 4; ++m) {
            int R = wrow * 64 + m * 16 + lx;
            af[m] = *(const f16x8*)(bA + R * 64 + ((quad ^ (R & 3)) * 16));
        }
#pragma unroll
        for (int n = 0; n < 4; ++n) {
            int R = wcol * 64 + n * 16 + lx;
            bf[n] = *(const f16x8*)(bB + R * 64 + ((quad ^ (R & 3)) * 16));
        }
#pragma unroll
        for (int m = 0; m < 4; ++m)
#pragma unroll
            for (int n = 0; n < 4; ++n)
                acc[m][n] = MFMA16(af[m], bf[n], acc[m][n]);
    }

#pragma unroll
    for (int m = 0; m < 4; ++m)
#pragma unroll
        for (int n = 0; n < 4; ++n)
#pragma unroll
            for (int r = 0; r < 4; ++r) {
                int row = m0 + wrow * 64 + m * 16 + quad * 4 + r;
                int col = n0 + wcol * 64 + n * 16 + lx;
                Wfb[(size_t)row * H_ + col] = (f16)acc[m][n][r];
            }
}

// ---------------- fused per-step kernel (no-LDS direct-VGPR) ----------------
// grid (64 jt(16 j), 4 mb(64 batch), 3 cells), block 128 = 2 waves.
// Each block owns a 64 batch x 64 col output tile (16 j x 4 gates; col c = n*16+lx
// -> gate=n, j=jt*16+lx -> lane-local LSTM update). The 2 waves SPLIT K
// (wave0 iters [0,nh), wave1 [nh,ntot)) and combine partials via one LDS exchange.
// Every fragment load is a contiguous, coalesced 1KB per wave straight to VGPR
// (packed layouts), 2-stage register prefetch, NO staging LDS, no inner barriers.
__global__ __launch_bounds__(128) void step_mfma(
    const f16* __restrict__ seqpk,    // [T][5][256][32]
    const f16* __restrict__ h2pkP,    // [32][256][32] prev h2 packed (zeros at t=0)
    const f16* __restrict__ h01pkC,   // [2][32][256][32] old h0,h1 packed
    f16* __restrict__ h01pkN,         // [2][32][256][32] new h0,h1 packed
    f16* __restrict__ h2pkN,          // [32][256][32] new h2 packed
    f16* __restrict__ histN,          // [256][1024] linear h2 for decode (hist + t*BH)
    float* __restrict__ c_st,         // [3][B][H]
    const f16* __restrict__ W0pk,     // [64][5][2048]
    const f16* __restrict__ Wpk,      // [6][64][32][2048]
    const float* __restrict__ bias_comb,  // [3][4096]
    const float* __restrict__ bfb,        // [4096]
    const int* __restrict__ cnum, const int* __restrict__ gnum,
    int t)
{
    const int jt   = blockIdx.x;
    const int mb   = blockIdx.y;
    const int l    = blockIdx.z;
    const int tid  = threadIdx.x;
    const int lane = tid & 63;
    const int w    = tid >> 6;         // 0/1 : K-split half
    const int lx   = lane & 15;
    const int quad = lane >> 4;

    __shared__ float ex[2][2][4][4][64];   // 16 KB combine buffer

    // ---- operand decode (byte pointers; per-kk strides: A 16KB, B 4KB)
    bool use_gt = false;
    int n0 = 32;
    const char *A0 = nullptr, *B0 = nullptr;
    const char* wbase = (const char*)Wpk + (size_t)jt * 131072;   // + wsel*8MB
    if (l == 0) {
        int cn = cnum[0], gn = gnum[0];
        use_gt = (t % (cn + gn)) < gn;
        if (use_gt)      { A0 = (const char*)(seqpk + (size_t)t * 40960);
                           B0 = (const char*)(W0pk + (size_t)jt * 10240); n0 = 5; }
        else if (t == 0) { n0 = 0; }
        else             { A0 = (const char*)h2pkP; B0 = wbase + (size_t)5 * 8388608; }
    } else if (l == 1) { A0 = (const char*)h01pkC;        B0 = wbase + (size_t)1 * 8388608; }
    else               { A0 = (const char*)(h01pkC + BH); B0 = wbase + (size_t)3 * 8388608; }
    const char* A1 = (l == 0) ? (const char*)h01pkC
                   : (l == 1) ? (const char*)(h01pkC + BH) : (const char*)h2pkP;
    const char* B1 = wbase + (size_t)((l == 0) ? 0 : (l == 1) ? 2 : 4) * 8388608;
    const int ntot = n0 + 32;
    const int nh = (ntot + 1) >> 1;
    const int lo = w ? nh : 0;
    const int hi = w ? ntot : nh;

    const int aoff = (mb * 64 + lx) * 64 + quad * 16;
    const int boff = lx * 64 + quad * 16;

    f32x4 acc[4][4];
#pragma unroll
    for (int m = 0; m < 4; ++m)
#pragma unroll
        for (int n = 0; n < 4; ++n) acc[m][n] = (f32x4){0.f, 0.f, 0.f, 0.f};

    f16x8 a0[4], b0[4], a1r[4], b1r[4];

    auto LD = [&](f16x8 (&aa)[4], f16x8 (&bb)[4], int it) {
        int kk; const char *pa, *pb;
        if (it < n0) { kk = it;      pa = A0; pb = B0; }
        else         { kk = it - n0; pa = A1; pb = B1; }
        pa += (size_t)kk * 16384 + aoff;
        pb += (size_t)kk * 4096 + boff;
#pragma unroll
        for (int m = 0; m < 4; ++m) aa[m] = *(const f16x8*)(pa + m * 1024);
#pragma unroll
        for (int n = 0; n < 4; ++n) bb[n] = *(const f16x8*)(pb + n * 1024);
    };
    auto MF = [&](f16x8 (&aa)[4], f16x8 (&bb)[4]) {
#pragma unroll
        for (int m = 0; m < 4; ++m)
#pragma unroll
            for (int n = 0; n < 4; ++n)
                acc[m][n] = MFMA16(aa[m], bb[n], acc[m][n]);
    };

    int it = lo;
    if (it < hi) LD(a0, b0, it);
    for (; it + 2 <= hi; it += 2) {
        LD(a1r, b1r, it + 1);
        MF(a0, b0);
        if (it + 2 < hi) LD(a0, b0, it + 2);
        MF(a1r, b1r);
    }
    if (it < hi) MF(a0, b0);          // odd remainder sits in a0/b0

    // ---- K-combine: wave1 publishes rows 0..31 partials, wave0 rows 32..63
#pragma unroll
    for (int m2 = 0; m2 < 2; ++m2)
#pragma unroll
        for (int n = 0; n < 4; ++n)
#pragma unroll
            for (int r = 0; r < 4; ++r) {
                if (w == 1) ex[0][m2][n][r][lane] = acc[m2][n][r];
                else        ex[1][m2][n][r][lane] = acc[2 + m2][n][r];
            }
    __syncthreads();

    f32x4 fa[2][4];
    if (w == 0) {
#pragma unroll
        for (int m2 = 0; m2 < 2; ++m2)
#pragma unroll
            for (int n = 0; n < 4; ++n) fa[m2][n] = acc[m2][n];
    } else {
#pragma unroll
        for (int m2 = 0; m2 < 2; ++m2)
#pragma unroll
            for (int n = 0; n < 4; ++n) fa[m2][n] = acc[2 + m2][n];
    }

    // ---- lane-local LSTM epilogue (wave w owns rows (w*2+m2)*16 .. +15)
    const int j = jt * 16 + lx;
    const float* bc = bias_comb + l * 4096;
    const bool addfb = (l == 0 && !use_gt && t > 0);
    float bi  = bc[j]        + (addfb ? bfb[j]        : 0.f);
    float bff = bc[1024 + j] + (addfb ? bfb[1024 + j] : 0.f);
    float bg  = bc[2048 + j] + (addfb ? bfb[2048 + j] : 0.f);
    float bo  = bc[3072 + j] + (addfb ? bfb[3072 + j] : 0.f);
#pragma unroll
    for (int m2 = 0; m2 < 2; ++m2) {
#pragma unroll
        for (int r = 0; r < 4; ++r) {
            int b = mb * 64 + (w * 2 + m2) * 16 + quad * 4 + r;
            float gi = fa[m2][0][r] + ex[w][m2][0][r][lane] + bi;
            float gf = fa[m2][1][r] + ex[w][m2][1][r][lane] + bff;
            float gg = fa[m2][2][r] + ex[w][m2][2][r][lane] + bg;
            float go = fa[m2][3][r] + ex[w][m2][3][r][lane] + bo;
            size_t ix = ((size_t)l * B_ + b) * H_ + j;
            float cn = sigmoidf_(gf) * c_st[ix] + sigmoidf_(gi) * tanhf_(gg);
            c_st[ix] = cn;
            float hv = sigmoidf_(go) * tanhf_(cn);
            f16 hv16 = (f16)hv;
            size_t pix = ((size_t)(j >> 5) * 256 + b) * 32 + (j & 31);   // packed
            if (l == 2) { h2pkN[pix] = hv16; histN[(size_t)b * H_ + j] = hv16; }
            else        h01pkN[(size_t)l * BH + pix] = hv16;
        }
    }
}

// ---------------- final batched decoder ----------------
// out[b][t][n] = hist[t][b][:] @ Wd^T + bd. M=25600 rows (t*256+b), N=160(132), K=1024.
// grid (200, 5), block 256 (4 waves stacked on M; tile 128x32).
__global__ __launch_bounds__(256) void decode_mfma(
    const f16* __restrict__ hist,   // [100][256][1024]
    const f16* __restrict__ Wd16,   // [160][1024]
    const float* __restrict__ bd,   // [132]
    float* __restrict__ dout)       // [256][T*132]
{
    const int r0  = blockIdx.x * 128;
    const int nb0 = blockIdx.y * 32;
    const int tid  = threadIdx.x;
    const int lane = tid & 63;
    const int w    = tid >> 6;
    const int lx   = lane & 15;
    const int quad = lane >> 4;

    __shared__ __align__(16) char lds[20480];   // 2 x (A 8KB + B 2KB)

    auto stA = [&](int kt, int buf) {
        char* base = lds + buf * 10240;
#pragma unroll
        for (int i = 0; i < 2; ++i) {
            int r  = w * 32 + i * 16 + (lane >> 2);
            int sg = (lane & 3) ^ (r & 3);
            const f16* g = hist + (size_t)(r0 + r) * H_ + kt * 32 + sg * 8;
            gl_lds16(g, base + (size_t)(w * 32 + i * 16) * 64);
        }
    };
    auto stB = [&](int kt, int buf) {
        char* base = lds + 8192 + buf * 10240;
        if (w < 2) {
            int r  = w * 16 + (lane >> 2);
            int sg = (lane & 3) ^ (r & 3);
            const f16* g = Wd16 + (size_t)(nb0 + r) * H_ + kt * 32 + sg * 8;
            gl_lds16(g, base + (size_t)(w * 16) * 64);
        }
    };

    f32x4 acc[2][2];
#pragma unroll
    for (int m = 0; m < 2; ++m)
#pragma unroll
        for (int n = 0; n < 2; ++n) acc[m][n] = (f32x4){0.f, 0.f, 0.f, 0.f};

    stA(0, 0); stB(0, 0);
    for (int kt = 0; kt < 32; ++kt) {
        __syncthreads();
        if (kt + 1 < 32) { stA(kt + 1, (kt + 1) & 1); stB(kt + 1, (kt + 1) & 1); }
        const char* bA = lds + (kt & 1) * 10240;
        const char* bB = lds + 8192 + (kt & 1) * 10240;
        f16x8 af[2], bf[2];
#pragma unroll
        for (int m = 0; m < 2; ++m) {
            int R = w * 32 + m * 16 + lx;
            af[m] = *(const f16x8*)(bA + R * 64 + ((quad ^ (R & 3)) * 16));
        }
#pragma unroll
        for (int n = 0; n < 2; ++n) {
            int R = n * 16 + lx;
            bf[n] = *(const f16x8*)(bB + R * 64 + ((quad ^ (R & 3)) * 16));
        }
#pragma unroll
        for (int m = 0; m < 2; ++m)
#pragma unroll
            for (int n = 0; n < 2; ++n)
                acc[m][n] = MFMA16(af[m], bf[n], acc[m][n]);
    }

#pragma unroll
    for (int n = 0; n < 2; ++n) {
        int nn = nb0 + n * 16 + lx;
        if (nn < OUT_) {
            float bv = bd[nn];
#pragma unroll
            for (int m = 0; m < 2; ++m)
#pragma unroll
                for (int r = 0; r < 4; ++r) {
                    int row = r0 + w * 32 + m * 16 + quad * 4 + r;
                    int tt = row >> 8, b = row & 255;
                    dout[(size_t)b * (T_ * OUT_) + (size_t)tt * OUT_ + nn] = acc[m][n][r] + bv;
                }
        }
    }
}

// ---------------- host launch ----------------

extern "C" void kernel_launch(void* const* d_in, const int* in_sizes, int n_in,
                              void* d_out, int out_size, void* d_ws, size_t ws_size,
                              hipStream_t stream) {
    const float* seq  = (const float*)d_in[0];
    const float* Wih1 = (const float*)d_in[1];
    const float* Whh1 = (const float*)d_in[2];
    const float* bih1 = (const float*)d_in[3];
    const float* bhh1 = (const float*)d_in[4];
    const float* Wih2 = (const float*)d_in[5];
    const float* Whh2 = (const float*)d_in[6];
    const float* bih2 = (const float*)d_in[7];
    const float* bhh2 = (const float*)d_in[8];
    const float* Wih3 = (const float*)d_in[9];
    const float* Whh3 = (const float*)d_in[10];
    const float* bih3 = (const float*)d_in[11];
    const float* bhh3 = (const float*)d_in[12];
    const float* Wd   = (const float*)d_in[13];
    const float* bd   = (const float*)d_in[14];
    const int*   cnum = (const int*)d_in[15];
    const int*   gnum = (const int*)d_in[16];

    // ---- workspace layout
    char* p = (char*)d_ws;
    f16*  W0   = (f16*)p;  p += (size_t)4096 * 160 * 2;          // 1.31 MB
    f16*  Wd16 = (f16*)p;  p += (size_t)160 * 1024 * 2;          // 0.33 MB
    f16*  WdT  = (f16*)p;  p += (size_t)1024 * 160 * 2;          // 0.33 MB
    f16*  Wfb  = (f16*)p;  p += (size_t)4096 * 1024 * 2;         // 8.39 MB
    float* bias_comb = (float*)p; p += (size_t)3 * 4096 * 4;     // 48 KB
    float* bfb = (float*)p; p += (size_t)4096 * 4;               // 16 KB
    f16*  hist = (f16*)p;  p += (size_t)100 * BH * 2;            // 52.4 MB
    // zero region start: h01pkA + h2pkA + c_st (contiguous)
    f16*  h01pkA = (f16*)p; p += (size_t)2 * BH * 2;             // 1.05 MB
    f16*  h2pkA  = (f16*)p; p += (size_t)BH * 2;                 // 0.52 MB
    float* c_st  = (float*)p; p += (size_t)3 * BH * 4;           // 3.15 MB
    f16*  h01pkB = (f16*)p; p += (size_t)2 * BH * 2;             // 1.05 MB
    f16*  h2pkB  = (f16*)p; p += (size_t)BH * 2;                 // 0.52 MB
    f16*  Wpk   = (f16*)p; p += (size_t)6 * 64 * 32 * 2048 * 2;  // 50.3 MB
    f16*  W0pk  = (f16*)p; p += (size_t)64 * 5 * 2048 * 2;       // 1.31 MB
    f16*  seqpk = (f16*)p; p += (size_t)T_ * 5 * 256 * 32 * 2;   // 8.19 MB

    const int zero_floats = (int)(((size_t)3 * BH * 2 + (size_t)3 * BH * 4) / 4);

    // ---- prep
    conv_pad<<<dim3(1, 4096), 256, 0, stream>>>(Wih1, W0, 4096, IN_, 160);
    conv_pad<<<dim3(4, 160), 256, 0, stream>>>(Wd, Wd16, OUT_, H_, H_);
    convT_kernel<<<dim3(1, 1024), 256, 0, stream>>>(Wd, WdT);
    bias_add_kernel<<<16, 256, 0, stream>>>(bih1, bhh1, bias_comb + 0 * 4096, 4096);
    bias_add_kernel<<<16, 256, 0, stream>>>(bih2, bhh2, bias_comb + 1 * 4096, 4096);
    bias_add_kernel<<<16, 256, 0, stream>>>(bih3, bhh3, bias_comb + 2 * 4096, 4096);
    bfb_kernel<<<16, 256, 0, stream>>>(Wih1, bd, bfb);
    wfb_mfma<<<dim3(32, 8), 256, 0, stream>>>(W0, WdT, Wfb);
    // packed weights: wsel {0:Whh1, 1:Wih2, 2:Whh2, 3:Wih3, 4:Whh3, 5:Wfb}
    pack_w<<<dim3(64, 32), 256, 0, stream>>>(Whh1, Wpk, 0);
    pack_w<<<dim3(64, 32), 256, 0, stream>>>(Wih2, Wpk, 1);
    pack_w<<<dim3(64, 32), 256, 0, stream>>>(Whh2, Wpk, 2);
    pack_w<<<dim3(64, 32), 256, 0, stream>>>(Wih3, Wpk, 3);
    pack_w<<<dim3(64, 32), 256, 0, stream>>>(Whh3, Wpk, 4);
    pack_wf16<<<dim3(64, 32), 256, 0, stream>>>(Wfb, Wpk, 5);
    pack_w0<<<dim3(64, 5), 256, 0, stream>>>(Wih1, W0pk);
    pack_seq<<<dim3(5, T_), 256, 0, stream>>>(seq, seqpk);
    zero_kernel<<<512, 256, 0, stream>>>((float*)h01pkA, zero_floats);

    f16 *h01C = h01pkA, *h01N = h01pkB, *h2P = h2pkA, *h2N = h2pkB;
    for (int t = 0; t < T_; ++t) {
        step_mfma<<<dim3(64, 4, 3), 128, 0, stream>>>(
            seqpk, h2P, h01C, h01N, h2N, hist + (size_t)t * BH, c_st,
            W0pk, Wpk, bias_comb, bfb, cnum, gnum, t);
        f16* tmp;
        tmp = h01C; h01C = h01N; h01N = tmp;
        tmp = h2P;  h2P  = h2N;  h2N  = tmp;
    }

    decode_mfma<<<dim3(200, 5), 256, 0, stream>>>(hist, Wd16, bd, (float*)d_out);
}